// Round 1
// baseline (19006.964 us; speedup 1.0000x reference)
//
#include <hip/hip_runtime.h>
#include <hip/hip_bf16.h>

#define SEQ 2048
#define DM 512
#define NHEAD 8
#define HDIM 64
#define DFFN 2048
#define PMTN 20

__device__ __forceinline__ float wave_sum(float v) {
#pragma unroll
  for (int off = 32; off; off >>= 1) v += __shfl_xor(v, off);
  return v;
}

// ---------------- embed: X = trg @ emb_w + emb_b  (2048x3 @ 3x512) ----------
__global__ __launch_bounds__(256) void embed_kernel(
    const float* __restrict__ trg, const float* __restrict__ w,
    const float* __restrict__ b, float* __restrict__ X) {
  int idx = blockIdx.x * 256 + threadIdx.x;   // 2048*512 total
  int r = idx >> 9, c = idx & 511;
  float t0 = trg[r * 3 + 0], t1 = trg[r * 3 + 1], t2 = trg[r * 3 + 2];
  X[idx] = t0 * w[c] + t1 * w[512 + c] + t2 * w[1024 + c] + b[c];
}

// ---------------- layernorm: one wave per row (512 elems, 8/lane) ----------
__global__ __launch_bounds__(64) void ln_kernel(
    const float* __restrict__ x, const float* __restrict__ g,
    const float* __restrict__ b, float* __restrict__ o) {
  int row = blockIdx.x, lane = threadIdx.x;
  const float* xr = x + row * DM;
  float v[8];
  float s = 0.f;
#pragma unroll
  for (int j = 0; j < 8; j++) { v[j] = xr[lane + 64 * j]; s += v[j]; }
  s = wave_sum(s);
  float mean = s * (1.f / DM);
  float q = 0.f;
#pragma unroll
  for (int j = 0; j < 8; j++) { float d = v[j] - mean; q += d * d; }
  q = wave_sum(q);
  float r = rsqrtf(q * (1.f / DM) + 1e-5f);
  float* orow = o + row * DM;
#pragma unroll
  for (int j = 0; j < 8; j++) {
    int c = lane + 64 * j;
    orow[c] = (v[j] - mean) * r * g[c] + b[c];
  }
}

// ---------------- generic fp32 GEMM: C[M,N] = A[M,K]@B[K,N] + bias (+res, relu)
// 64x64 block tile, 256 threads, 4x4 per thread, K-step 16.
// All M,N multiples of 64 and K multiples of 16 in this model.
__global__ __launch_bounds__(256) void gemm64(
    const float* __restrict__ A, int lda,
    const float* __restrict__ B, int ldb,
    const float* __restrict__ bias,
    const float* __restrict__ residual,
    float* __restrict__ C, int ldc, int K, int relu) {
  __shared__ float As[16][65];
  __shared__ float Bs[16][65];
  int n0 = blockIdx.x * 64;
  int m0 = blockIdx.y * 64;
  int t = threadIdx.x;
  int am = t >> 2;          // 0..63
  int ak = (t & 3) * 4;     // 0,4,8,12
  int bk = t >> 4;          // 0..15
  int bn = (t & 15) * 4;    // 0..60
  int tm = (t >> 4) * 4;    // row group
  int tn = (t & 15) * 4;    // col group
  float acc[4][4] = {};
  for (int k0 = 0; k0 < K; k0 += 16) {
    float4 av = *(const float4*)(A + (long)(m0 + am) * lda + k0 + ak);
    float4 bv = *(const float4*)(B + (long)(k0 + bk) * ldb + n0 + bn);
    __syncthreads();
    As[ak + 0][am] = av.x; As[ak + 1][am] = av.y;
    As[ak + 2][am] = av.z; As[ak + 3][am] = av.w;
    Bs[bk][bn + 0] = bv.x; Bs[bk][bn + 1] = bv.y;
    Bs[bk][bn + 2] = bv.z; Bs[bk][bn + 3] = bv.w;
    __syncthreads();
#pragma unroll
    for (int kk = 0; kk < 16; kk++) {
      float a[4], bb[4];
#pragma unroll
      for (int i = 0; i < 4; i++) a[i] = As[kk][tm + i];
#pragma unroll
      for (int j = 0; j < 4; j++) bb[j] = Bs[kk][tn + j];
#pragma unroll
      for (int i = 0; i < 4; i++)
#pragma unroll
        for (int j = 0; j < 4; j++) acc[i][j] = fmaf(a[i], bb[j], acc[i][j]);
    }
  }
#pragma unroll
  for (int i = 0; i < 4; i++) {
    int m = m0 + tm + i;
#pragma unroll
    for (int j = 0; j < 4; j++) {
      int n = n0 + tn + j;
      float c = acc[i][j] + bias[n];
      if (relu) c = fmaxf(c, 0.f);
      if (residual) c += residual[(long)m * ldc + n];
      C[(long)m * ldc + n] = c;
    }
  }
}

// ---------------- RoPE (in place) on q (ldq) and k (ldk), half=32 -----------
__global__ __launch_bounds__(256) void rope_kernel(float* __restrict__ q, int ldq,
                                                   float* __restrict__ k, int ldk) {
  int row = blockIdx.x;
  int t = threadIdx.x;            // 256 = 8 heads * 32 freqs
  int head = t >> 5, i = t & 31;
  float inv = expf(-(float)i * (9.210340371976184f / 32.f));  // 10000^(-i/32)
  float ang = (float)row * inv;
  float sn, cs;
  sincosf(ang, &sn, &cs);
  {
    float* p = q + (long)row * ldq + head * 64;
    float x1 = p[i], x2 = p[i + 32];
    p[i] = x1 * cs - x2 * sn;
    p[i + 32] = x1 * sn + x2 * cs;
  }
  {
    float* p = k + (long)row * ldk + head * 64;
    float x1 = p[i], x2 = p[i + 32];
    p[i] = x1 * cs - x2 * sn;
    p[i + 32] = x1 * sn + x2 * cs;
  }
}

// ---------------- streaming attention: 1 wave per (qrow, head) --------------
__global__ __launch_bounds__(64) void attn_kernel(
    const float* __restrict__ Q, int ldq,
    const float* __restrict__ Kb, int ldk,
    const float* __restrict__ Vb, int ldv,
    const float* __restrict__ mask,
    float* __restrict__ O, int ldo, int sk, int causal) {
  int qrow = blockIdx.x, head = blockIdx.y, lane = threadIdx.x;
  float qd = Q[(long)qrow * ldq + head * 64 + lane];
  const float* Kh = Kb + head * 64 + lane;
  const float* Vh = Vb + head * 64 + lane;
  int klim = causal ? (qrow + 1) : sk;
  float m = -1e30f, l = 0.f, acc = 0.f;
  for (int k0 = 0; k0 < klim; k0 += 4) {
    float s[4];
#pragma unroll
    for (int j = 0; j < 4; j++) {
      int kk = k0 + j;
      float d = (kk < klim) ? qd * Kh[(long)kk * ldk] : 0.f;
      d = wave_sum(d);
      float mv = 0.f;
      if (kk < klim) mv = (mask[kk] > 0.f) ? 0.f : -1e9f;
      s[j] = (kk < klim) ? (d * 0.125f + mv) : -1e30f;
    }
    float cm = m;
#pragma unroll
    for (int j = 0; j < 4; j++) cm = fmaxf(cm, s[j]);
    float sc = __expf(m - cm);
    l *= sc;
    acc *= sc;
#pragma unroll
    for (int j = 0; j < 4; j++) {
      int kk = k0 + j;
      float p = __expf(s[j] - cm);
      float vv = (kk < klim) ? Vh[(long)kk * ldv] : 0.f;
      l += p;
      acc = fmaf(p, vv, acc);
    }
    m = cm;
  }
  O[(long)qrow * ldo + head * 64 + lane] = acc / l;
}

// ---------------- generator: out[r,0..2] = h[r,:] @ gen_w + gen_b ----------
__global__ __launch_bounds__(64) void gen_kernel(
    const float* __restrict__ h, const float* __restrict__ gw,
    const float* __restrict__ gb, float* __restrict__ out) {
  int row = blockIdx.x, lane = threadIdx.x;
  float a0 = 0.f, a1 = 0.f, a2 = 0.f;
  for (int k = lane; k < DM; k += 64) {
    float x = h[(long)row * DM + k];
    a0 = fmaf(x, gw[k * 3 + 0], a0);
    a1 = fmaf(x, gw[k * 3 + 1], a1);
    a2 = fmaf(x, gw[k * 3 + 2], a2);
  }
  a0 = wave_sum(a0);
  a1 = wave_sum(a1);
  a2 = wave_sum(a2);
  if (lane == 0) {
    out[row * 3 + 0] = a0 + gb[0];
    out[row * 3 + 1] = a1 + gb[1];
    out[row * 3 + 2] = a2 + gb[2];
  }
}

extern "C" void kernel_launch(void* const* d_in, const int* in_sizes, int n_in,
                              void* d_out, int out_size, void* d_ws, size_t ws_size,
                              hipStream_t stream) {
  const float* trg      = (const float*)d_in[0];
  const float* src_rep  = (const float*)d_in[1];
  const float* src_mask = (const float*)d_in[2];
  const float* emb_w    = (const float*)d_in[3];
  const float* emb_b    = (const float*)d_in[4];
  const float* sa_wqkv  = (const float*)d_in[5];
  const float* sa_bqkv  = (const float*)d_in[6];
  const float* sa_wo    = (const float*)d_in[7];
  const float* sa_bo    = (const float*)d_in[8];
  const float* ca_wqkv  = (const float*)d_in[9];
  const float* ca_bqkv  = (const float*)d_in[10];
  const float* ca_wo    = (const float*)d_in[11];
  const float* ca_bo    = (const float*)d_in[12];
  const float* ffn_w1   = (const float*)d_in[13];
  const float* ffn_b1   = (const float*)d_in[14];
  const float* ffn_w2   = (const float*)d_in[15];
  const float* ffn_b2   = (const float*)d_in[16];
  const float* ln_g     = (const float*)d_in[17];
  const float* ln_b     = (const float*)d_in[18];
  const float* lnf_g    = (const float*)d_in[19];
  const float* lnf_b    = (const float*)d_in[20];
  const float* gen_w    = (const float*)d_in[21];
  const float* gen_b    = (const float*)d_in[22];

  const float* srb = src_rep + (long)PMTN * DM;  // (2048, 512)

  float* ws = (float*)d_ws;
  float* X   = ws;                         // 2048*512
  float* Hb  = X + (long)SEQ * DM;         // 2048*512
  float* QKV = Hb + (long)SEQ * DM;        // 2048*1536
  float* AO  = QKV + (long)SEQ * 3 * DM;   // 2048*512
  float* MID = QKV;                        // 2048*2048 aliases QKV+AO (free then)

  // embed
  embed_kernel<<<(SEQ * DM) / 256, 256, 0, stream>>>(trg, emb_w, emb_b, X);

  for (int li = 0; li < 4; li++) {
    const float* wqkv = sa_wqkv + (long)li * DM * 3 * DM;
    const float* bqkv = sa_bqkv + (long)li * 3 * DM;
    const float* wo   = sa_wo + (long)li * DM * DM;
    const float* bo   = sa_bo + (long)li * DM;
    const float* cwqkv = ca_wqkv + (long)li * DM * 3 * DM;
    const float* cbqkv = ca_bqkv + (long)li * 3 * DM;
    const float* cwo   = ca_wo + (long)li * DM * DM;
    const float* cbo   = ca_bo + (long)li * DM;
    const float* w1 = ffn_w1 + (long)li * DM * DFFN;
    const float* b1 = ffn_b1 + (long)li * DFFN;
    const float* w2 = ffn_w2 + (long)li * DFFN * DM;
    const float* b2 = ffn_b2 + (long)li * DM;
    const float* g0 = ln_g + (long)(li * 3 + 0) * DM;
    const float* b0 = ln_b + (long)(li * 3 + 0) * DM;
    const float* g1 = ln_g + (long)(li * 3 + 1) * DM;
    const float* b1n = ln_b + (long)(li * 3 + 1) * DM;
    const float* g2 = ln_g + (long)(li * 3 + 2) * DM;
    const float* b2n = ln_b + (long)(li * 3 + 2) * DM;

    // ---- self attention ----
    ln_kernel<<<SEQ, 64, 0, stream>>>(X, g0, b0, Hb);
    gemm64<<<dim3(3 * DM / 64, SEQ / 64), 256, 0, stream>>>(
        Hb, DM, wqkv, 3 * DM, bqkv, nullptr, QKV, 3 * DM, DM, 0);
    rope_kernel<<<SEQ, 256, 0, stream>>>(QKV, 3 * DM, QKV + DM, 3 * DM);
    attn_kernel<<<dim3(SEQ, NHEAD), 64, 0, stream>>>(
        QKV, 3 * DM, QKV + DM, 3 * DM, QKV + 2 * DM, 3 * DM, src_mask,
        AO, DM, SEQ, 1);
    gemm64<<<dim3(DM / 64, SEQ / 64), 256, 0, stream>>>(
        AO, DM, wo, DM, bo, X, X, DM, DM, 0);

    // ---- cross attention ----
    ln_kernel<<<SEQ, 64, 0, stream>>>(X, g1, b1n, Hb);
    // q = Hb @ cwqkv[:, :512]
    gemm64<<<dim3(DM / 64, SEQ / 64), 256, 0, stream>>>(
        Hb, DM, cwqkv, 3 * DM, cbqkv, nullptr, QKV, DM, DM, 0);
    // kv = srb @ cwqkv[:, 512:]
    gemm64<<<dim3(2 * DM / 64, SEQ / 64), 256, 0, stream>>>(
        srb, DM, cwqkv + DM, 3 * DM, cbqkv + DM, nullptr,
        QKV + (long)SEQ * DM, 2 * DM, DM, 0);
    rope_kernel<<<SEQ, 256, 0, stream>>>(QKV, DM, QKV + (long)SEQ * DM, 2 * DM);
    attn_kernel<<<dim3(SEQ, NHEAD), 64, 0, stream>>>(
        QKV, DM, QKV + (long)SEQ * DM, 2 * DM,
        QKV + (long)SEQ * DM + DM, 2 * DM, src_mask, AO, DM, SEQ, 0);
    gemm64<<<dim3(DM / 64, SEQ / 64), 256, 0, stream>>>(
        AO, DM, cwo, DM, cbo, X, X, DM, DM, 0);

    // ---- FFN ----
    ln_kernel<<<SEQ, 64, 0, stream>>>(X, g2, b2n, Hb);
    gemm64<<<dim3(DFFN / 64, SEQ / 64), 256, 0, stream>>>(
        Hb, DM, w1, DFFN, b1, nullptr, MID, DFFN, DM, 1);
    gemm64<<<dim3(DM / 64, SEQ / 64), 256, 0, stream>>>(
        MID, DFFN, w2, DM, b2, X, X, DM, DFFN, 0);
  }

  ln_kernel<<<SEQ, 64, 0, stream>>>(X, lnf_g, lnf_b, Hb);
  gen_kernel<<<SEQ, 64, 0, stream>>>(Hb, gen_w, gen_b, (float*)d_out);
}

// Round 2
// 3250.330 us; speedup vs baseline: 5.8477x; 5.8477x over previous
//
#include <hip/hip_runtime.h>
#include <hip/hip_bf16.h>

#define SEQ 2048
#define DM 512
#define NHEAD 8
#define HDIM 64
#define DFFN 2048
#define PMTN 20

__device__ __forceinline__ float wave_sum(float v) {
#pragma unroll
  for (int off = 32; off; off >>= 1) v += __shfl_xor(v, off);
  return v;
}

// ---------------- embed: X = trg @ emb_w + emb_b  (2048x3 @ 3x512) ----------
__global__ __launch_bounds__(256) void embed_kernel(
    const float* __restrict__ trg, const float* __restrict__ w,
    const float* __restrict__ b, float* __restrict__ X) {
  int idx = blockIdx.x * 256 + threadIdx.x;   // 2048*512 total
  int r = idx >> 9, c = idx & 511;
  float t0 = trg[r * 3 + 0], t1 = trg[r * 3 + 1], t2 = trg[r * 3 + 2];
  X[idx] = t0 * w[c] + t1 * w[512 + c] + t2 * w[1024 + c] + b[c];
}

// ---------------- layernorm: one wave per row (512 elems, 8/lane) ----------
__global__ __launch_bounds__(64) void ln_kernel(
    const float* __restrict__ x, const float* __restrict__ g,
    const float* __restrict__ b, float* __restrict__ o) {
  int row = blockIdx.x, lane = threadIdx.x;
  const float* xr = x + row * DM;
  float v[8];
  float s = 0.f;
#pragma unroll
  for (int j = 0; j < 8; j++) { v[j] = xr[lane + 64 * j]; s += v[j]; }
  s = wave_sum(s);
  float mean = s * (1.f / DM);
  float q = 0.f;
#pragma unroll
  for (int j = 0; j < 8; j++) { float d = v[j] - mean; q += d * d; }
  q = wave_sum(q);
  float r = rsqrtf(q * (1.f / DM) + 1e-5f);
  float* orow = o + row * DM;
#pragma unroll
  for (int j = 0; j < 8; j++) {
    int c = lane + 64 * j;
    orow[c] = (v[j] - mean) * r * g[c] + b[c];
  }
}

// ---------------- generic fp32 GEMM: C[M,N] = A[M,K]@B[K,N] + bias (+res, relu)
__global__ __launch_bounds__(256) void gemm64(
    const float* __restrict__ A, int lda,
    const float* __restrict__ B, int ldb,
    const float* __restrict__ bias,
    const float* __restrict__ residual,
    float* __restrict__ C, int ldc, int K, int relu) {
  __shared__ float As[16][65];
  __shared__ float Bs[16][65];
  int n0 = blockIdx.x * 64;
  int m0 = blockIdx.y * 64;
  int t = threadIdx.x;
  int am = t >> 2;
  int ak = (t & 3) * 4;
  int bk = t >> 4;
  int bn = (t & 15) * 4;
  int tm = (t >> 4) * 4;
  int tn = (t & 15) * 4;
  float acc[4][4] = {};
  for (int k0 = 0; k0 < K; k0 += 16) {
    float4 av = *(const float4*)(A + (long)(m0 + am) * lda + k0 + ak);
    float4 bv = *(const float4*)(B + (long)(k0 + bk) * ldb + n0 + bn);
    __syncthreads();
    As[ak + 0][am] = av.x; As[ak + 1][am] = av.y;
    As[ak + 2][am] = av.z; As[ak + 3][am] = av.w;
    Bs[bk][bn + 0] = bv.x; Bs[bk][bn + 1] = bv.y;
    Bs[bk][bn + 2] = bv.z; Bs[bk][bn + 3] = bv.w;
    __syncthreads();
#pragma unroll
    for (int kk = 0; kk < 16; kk++) {
      float a[4], bb[4];
#pragma unroll
      for (int i = 0; i < 4; i++) a[i] = As[kk][tm + i];
#pragma unroll
      for (int j = 0; j < 4; j++) bb[j] = Bs[kk][tn + j];
#pragma unroll
      for (int i = 0; i < 4; i++)
#pragma unroll
        for (int j = 0; j < 4; j++) acc[i][j] = fmaf(a[i], bb[j], acc[i][j]);
    }
  }
#pragma unroll
  for (int i = 0; i < 4; i++) {
    int m = m0 + tm + i;
#pragma unroll
    for (int j = 0; j < 4; j++) {
      int n = n0 + tn + j;
      float c = acc[i][j] + bias[n];
      if (relu) c = fmaxf(c, 0.f);
      if (residual) c += residual[(long)m * ldc + n];
      C[(long)m * ldc + n] = c;
    }
  }
}

// ---------------- RoPE (in place) on q (ldq) and k (ldk), half=32 -----------
__global__ __launch_bounds__(256) void rope_kernel(float* __restrict__ q, int ldq,
                                                   float* __restrict__ k, int ldk) {
  int row = blockIdx.x;
  int t = threadIdx.x;
  int head = t >> 5, i = t & 31;
  float inv = expf(-(float)i * (9.210340371976184f / 32.f));
  float ang = (float)row * inv;
  float sn, cs;
  sincosf(ang, &sn, &cs);
  {
    float* p = q + (long)row * ldq + head * 64;
    float x1 = p[i], x2 = p[i + 32];
    p[i] = x1 * cs - x2 * sn;
    p[i + 32] = x1 * sn + x2 * cs;
  }
  {
    float* p = k + (long)row * ldk + head * 64;
    float x1 = p[i], x2 = p[i + 32];
    p[i] = x1 * cs - x2 * sn;
    p[i + 32] = x1 * sn + x2 * cs;
  }
}

// ---------------- tiled flash attention ------------------------------------
// grid (SEQ/64, NHEAD), 256 threads. 64-row q-tile per block; 64-wide k-tiles.
// Qs/Ks stored transposed [d][k] with XOR-unit swizzle (conflict-free b128);
// Vs natural [k][d]; P transposed [k][q] swizzled.
__global__ __launch_bounds__(256) void attn_tile_kernel(
    const float* __restrict__ Q, int ldq,
    const float* __restrict__ K, int ldk,
    const float* __restrict__ V, int ldv,
    const float* __restrict__ mask,
    float* __restrict__ O, int ldo, int causal) {
  __shared__ float Qs[4096];
  __shared__ float Ks[4096];
  __shared__ float Vs[4096];
  __shared__ float Ps[4096];
  const int qt = blockIdx.x, head = blockIdx.y;
  const int t = threadIdx.x;
  const int q0 = qt * 64;
  const int g = t >> 4;        // 0..15 (row group)
  const int u = t & 15;        // 0..15 (col group)
  const int tm = g * 4;
  const int tn = u * 4;

  // stage Q tile transposed+swizzled: element (q=r, d) -> Qs[d*64 + 4*((r>>2 ^ d>>2)&15) + (r&3)]
#pragma unroll
  for (int p = 0; p < 4; p++) {
    int idx = t + p * 256;
    int r = idx >> 4, c = idx & 15;
    float4 v4 = *(const float4*)(Q + (long)(q0 + r) * ldq + head * 64 + 4 * c);
    float vv[4] = {v4.x, v4.y, v4.z, v4.w};
#pragma unroll
    for (int e = 0; e < 4; e++) {
      int d = 4 * c + e;
      Qs[d * 64 + 4 * (((r >> 2) ^ c) & 15) + (r & 3)] = vv[e];
    }
  }

  float m_i[4], l_i[4], o[4][4];
#pragma unroll
  for (int i = 0; i < 4; i++) {
    m_i[i] = -1e30f;
    l_i[i] = 0.f;
#pragma unroll
    for (int j = 0; j < 4; j++) o[i][j] = 0.f;
  }

  const int nkt = causal ? (qt + 1) : (SEQ / 64);
  for (int kt = 0; kt < nkt; kt++) {
    const int kbase = kt * 64;
    __syncthreads();  // previous tile's PV reads of Vs/Ps done
    // stage K transposed+swizzled, V natural
#pragma unroll
    for (int p = 0; p < 4; p++) {
      int idx = t + p * 256;
      int r = idx >> 4, c = idx & 15;
      float4 kv4 = *(const float4*)(K + (long)(kbase + r) * ldk + head * 64 + 4 * c);
      float kvv[4] = {kv4.x, kv4.y, kv4.z, kv4.w};
#pragma unroll
      for (int e = 0; e < 4; e++) {
        int d = 4 * c + e;
        Ks[d * 64 + 4 * (((r >> 2) ^ c) & 15) + (r & 3)] = kvv[e];
      }
      float4 vv4 = *(const float4*)(V + (long)(kbase + r) * ldv + head * 64 + 4 * c);
      *(float4*)&Vs[r * 64 + 4 * c] = vv4;
    }
    __syncthreads();

    // S = Q @ K^T : acc[i][j] = sum_d Q[tm+i][d] * K[tn+j][d]
    float acc[4][4] = {};
#pragma unroll
    for (int d4 = 0; d4 < 16; d4++) {
      int xa = 4 * ((g ^ d4) & 15);
      int xb = 4 * ((u ^ d4) & 15);
#pragma unroll
      for (int e = 0; e < 4; e++) {
        int base = (4 * d4 + e) * 64;
        float4 a4 = *(const float4*)&Qs[base + xa];
        float4 b4 = *(const float4*)&Ks[base + xb];
        float a_[4] = {a4.x, a4.y, a4.z, a4.w};
        float b_[4] = {b4.x, b4.y, b4.z, b4.w};
#pragma unroll
        for (int i = 0; i < 4; i++)
#pragma unroll
          for (int j = 0; j < 4; j++) acc[i][j] = fmaf(a_[i], b_[j], acc[i][j]);
      }
    }

    // mask columns
    float mv[4];
#pragma unroll
    for (int j = 0; j < 4; j++) mv[j] = mask[kbase + tn + j];

    // online softmax per row (16 threads with same g own one row set)
#pragma unroll
    for (int i = 0; i < 4; i++) {
      int qrow = q0 + tm + i;
      float s_[4];
#pragma unroll
      for (int j = 0; j < 4; j++) {
        float sv = acc[i][j] * 0.125f;
        bool valid = (mv[j] > 0.f) && (!causal || (kbase + tn + j) <= qrow);
        s_[j] = valid ? sv : -1e30f;
      }
      float rm = fmaxf(fmaxf(s_[0], s_[1]), fmaxf(s_[2], s_[3]));
#pragma unroll
      for (int off = 8; off; off >>= 1) rm = fmaxf(rm, __shfl_xor(rm, off));
      float nm = fmaxf(m_i[i], rm);
      float f = __expf(m_i[i] - nm);
      m_i[i] = nm;
      float p_[4], ps = 0.f;
#pragma unroll
      for (int j = 0; j < 4; j++) {
        p_[j] = (s_[j] > -1e29f) ? __expf(s_[j] - nm) : 0.f;
        ps += p_[j];
      }
#pragma unroll
      for (int off = 8; off; off >>= 1) ps += __shfl_xor(ps, off);
      l_i[i] = l_i[i] * f + ps;
#pragma unroll
      for (int j = 0; j < 4; j++) {
        o[i][j] *= f;
        // P transposed: element (kk=tn+j, q=tm+i)
        Ps[(tn + j) * 64 + 4 * ((g ^ u) & 15) + i] = p_[j];
      }
    }
    __syncthreads();

    // O += P @ V : o[i][j] += sum_kk P[tm+i][kk] * V[kk][tn+j]
#pragma unroll
    for (int k4 = 0; k4 < 16; k4++) {
      int xa = 4 * ((g ^ k4) & 15);
#pragma unroll
      for (int e = 0; e < 4; e++) {
        int kk = 4 * k4 + e;
        float4 a4 = *(const float4*)&Ps[kk * 64 + xa];
        float4 b4 = *(const float4*)&Vs[kk * 64 + tn];
        float a_[4] = {a4.x, a4.y, a4.z, a4.w};
        float b_[4] = {b4.x, b4.y, b4.z, b4.w};
#pragma unroll
        for (int i = 0; i < 4; i++)
#pragma unroll
          for (int j = 0; j < 4; j++) o[i][j] = fmaf(a_[i], b_[j], o[i][j]);
      }
    }
  }

  // write out
#pragma unroll
  for (int i = 0; i < 4; i++) {
    float inv = 1.f / l_i[i];
    float4 ov;
    ov.x = o[i][0] * inv; ov.y = o[i][1] * inv;
    ov.z = o[i][2] * inv; ov.w = o[i][3] * inv;
    *(float4*)(O + (long)(q0 + tm + i) * ldo + head * 64 + tn) = ov;
  }
}

// ---------------- generator: out[r,0..2] = h[r,:] @ gen_w + gen_b ----------
__global__ __launch_bounds__(64) void gen_kernel(
    const float* __restrict__ h, const float* __restrict__ gw,
    const float* __restrict__ gb, float* __restrict__ out) {
  int row = blockIdx.x, lane = threadIdx.x;
  float a0 = 0.f, a1 = 0.f, a2 = 0.f;
  for (int k = lane; k < DM; k += 64) {
    float x = h[(long)row * DM + k];
    a0 = fmaf(x, gw[k * 3 + 0], a0);
    a1 = fmaf(x, gw[k * 3 + 1], a1);
    a2 = fmaf(x, gw[k * 3 + 2], a2);
  }
  a0 = wave_sum(a0);
  a1 = wave_sum(a1);
  a2 = wave_sum(a2);
  if (lane == 0) {
    out[row * 3 + 0] = a0 + gb[0];
    out[row * 3 + 1] = a1 + gb[1];
    out[row * 3 + 2] = a2 + gb[2];
  }
}

extern "C" void kernel_launch(void* const* d_in, const int* in_sizes, int n_in,
                              void* d_out, int out_size, void* d_ws, size_t ws_size,
                              hipStream_t stream) {
  const float* trg      = (const float*)d_in[0];
  const float* src_rep  = (const float*)d_in[1];
  const float* src_mask = (const float*)d_in[2];
  const float* emb_w    = (const float*)d_in[3];
  const float* emb_b    = (const float*)d_in[4];
  const float* sa_wqkv  = (const float*)d_in[5];
  const float* sa_bqkv  = (const float*)d_in[6];
  const float* sa_wo    = (const float*)d_in[7];
  const float* sa_bo    = (const float*)d_in[8];
  const float* ca_wqkv  = (const float*)d_in[9];
  const float* ca_bqkv  = (const float*)d_in[10];
  const float* ca_wo    = (const float*)d_in[11];
  const float* ca_bo    = (const float*)d_in[12];
  const float* ffn_w1   = (const float*)d_in[13];
  const float* ffn_b1   = (const float*)d_in[14];
  const float* ffn_w2   = (const float*)d_in[15];
  const float* ffn_b2   = (const float*)d_in[16];
  const float* ln_g     = (const float*)d_in[17];
  const float* ln_b     = (const float*)d_in[18];
  const float* lnf_g    = (const float*)d_in[19];
  const float* lnf_b    = (const float*)d_in[20];
  const float* gen_w    = (const float*)d_in[21];
  const float* gen_b    = (const float*)d_in[22];

  const float* srb = src_rep + (long)PMTN * DM;

  float* ws = (float*)d_ws;
  float* X   = ws;
  float* Hb  = X + (long)SEQ * DM;
  float* QKV = Hb + (long)SEQ * DM;
  float* AO  = QKV + (long)SEQ * 3 * DM;
  float* MID = QKV;

  embed_kernel<<<(SEQ * DM) / 256, 256, 0, stream>>>(trg, emb_w, emb_b, X);

  for (int li = 0; li < 4; li++) {
    const float* wqkv = sa_wqkv + (long)li * DM * 3 * DM;
    const float* bqkv = sa_bqkv + (long)li * 3 * DM;
    const float* wo   = sa_wo + (long)li * DM * DM;
    const float* bo   = sa_bo + (long)li * DM;
    const float* cwqkv = ca_wqkv + (long)li * DM * 3 * DM;
    const float* cbqkv = ca_bqkv + (long)li * 3 * DM;
    const float* cwo   = ca_wo + (long)li * DM * DM;
    const float* cbo   = ca_bo + (long)li * DM;
    const float* w1 = ffn_w1 + (long)li * DM * DFFN;
    const float* b1 = ffn_b1 + (long)li * DFFN;
    const float* w2 = ffn_w2 + (long)li * DFFN * DM;
    const float* b2 = ffn_b2 + (long)li * DM;
    const float* g0 = ln_g + (long)(li * 3 + 0) * DM;
    const float* b0 = ln_b + (long)(li * 3 + 0) * DM;
    const float* g1 = ln_g + (long)(li * 3 + 1) * DM;
    const float* b1n = ln_b + (long)(li * 3 + 1) * DM;
    const float* g2 = ln_g + (long)(li * 3 + 2) * DM;
    const float* b2n = ln_b + (long)(li * 3 + 2) * DM;

    // ---- self attention ----
    ln_kernel<<<SEQ, 64, 0, stream>>>(X, g0, b0, Hb);
    gemm64<<<dim3(3 * DM / 64, SEQ / 64), 256, 0, stream>>>(
        Hb, DM, wqkv, 3 * DM, bqkv, nullptr, QKV, 3 * DM, DM, 0);
    rope_kernel<<<SEQ, 256, 0, stream>>>(QKV, 3 * DM, QKV + DM, 3 * DM);
    attn_tile_kernel<<<dim3(SEQ / 64, NHEAD), 256, 0, stream>>>(
        QKV, 3 * DM, QKV + DM, 3 * DM, QKV + 2 * DM, 3 * DM, src_mask,
        AO, DM, 1);
    gemm64<<<dim3(DM / 64, SEQ / 64), 256, 0, stream>>>(
        AO, DM, wo, DM, bo, X, X, DM, DM, 0);

    // ---- cross attention ----
    ln_kernel<<<SEQ, 64, 0, stream>>>(X, g1, b1n, Hb);
    gemm64<<<dim3(DM / 64, SEQ / 64), 256, 0, stream>>>(
        Hb, DM, cwqkv, 3 * DM, cbqkv, nullptr, QKV, DM, DM, 0);
    gemm64<<<dim3(2 * DM / 64, SEQ / 64), 256, 0, stream>>>(
        srb, DM, cwqkv + DM, 3 * DM, cbqkv + DM, nullptr,
        QKV + (long)SEQ * DM, 2 * DM, DM, 0);
    rope_kernel<<<SEQ, 256, 0, stream>>>(QKV, DM, QKV + (long)SEQ * DM, 2 * DM);
    attn_tile_kernel<<<dim3(SEQ / 64, NHEAD), 256, 0, stream>>>(
        QKV, DM, QKV + (long)SEQ * DM, 2 * DM,
        QKV + (long)SEQ * DM + DM, 2 * DM, src_mask, AO, DM, 0);
    gemm64<<<dim3(DM / 64, SEQ / 64), 256, 0, stream>>>(
        AO, DM, cwo, DM, cbo, X, X, DM, DM, 0);

    // ---- FFN ----
    ln_kernel<<<SEQ, 64, 0, stream>>>(X, g2, b2n, Hb);
    gemm64<<<dim3(DFFN / 64, SEQ / 64), 256, 0, stream>>>(
        Hb, DM, w1, DFFN, b1, nullptr, MID, DFFN, DM, 1);
    gemm64<<<dim3(DM / 64, SEQ / 64), 256, 0, stream>>>(
        MID, DFFN, w2, DM, b2, X, X, DM, DFFN, 0);
  }

  ln_kernel<<<SEQ, 64, 0, stream>>>(X, lnf_g, lnf_b, Hb);
  gen_kernel<<<SEQ, 64, 0, stream>>>(Hb, gen_w, gen_b, (float*)d_out);
}

// Round 3
// 1708.374 us; speedup vs baseline: 11.1258x; 1.9026x over previous
//
#include <hip/hip_runtime.h>
#include <hip/hip_bf16.h>

#define SEQ 2048
#define DM 512
#define NHEAD 8
#define HDIM 64
#define DFFN 2048
#define PMTN 20

typedef __bf16 bf16x8 __attribute__((ext_vector_type(8)));
typedef float f32x4 __attribute__((ext_vector_type(4)));

__device__ __forceinline__ float wave_sum(float v) {
#pragma unroll
  for (int off = 32; off; off >>= 1) v += __shfl_xor(v, off);
  return v;
}

__device__ __forceinline__ unsigned short f2b(float x) {
  __hip_bfloat16 h = __float2bfloat16(x);
  return *(unsigned short*)&h;
}

// ---------------- embed: X = trg @ emb_w + emb_b ----------------------------
__global__ __launch_bounds__(256) void embed_kernel(
    const float* __restrict__ trg, const float* __restrict__ w,
    const float* __restrict__ b, float* __restrict__ X) {
  int idx = blockIdx.x * 256 + threadIdx.x;
  int r = idx >> 9, c = idx & 511;
  float t0 = trg[r * 3 + 0], t1 = trg[r * 3 + 1], t2 = trg[r * 3 + 2];
  X[idx] = t0 * w[c] + t1 * w[512 + c] + t2 * w[1024 + c] + b[c];
}

// ---------------- fp32 -> bf16 cast -----------------------------------------
__global__ __launch_bounds__(256) void cast_bf16_kernel(
    const float* __restrict__ in, __hip_bfloat16* __restrict__ out) {
  int i = blockIdx.x * 256 + threadIdx.x;
  out[i] = __float2bfloat16(in[i]);
}

// ---------------- layernorm -> bf16 out -------------------------------------
__global__ __launch_bounds__(64) void ln_bf16_kernel(
    const float* __restrict__ x, const float* __restrict__ g,
    const float* __restrict__ b, __hip_bfloat16* __restrict__ o) {
  int row = blockIdx.x, lane = threadIdx.x;
  const float* xr = x + row * DM;
  float v[8];
  float s = 0.f;
#pragma unroll
  for (int j = 0; j < 8; j++) { v[j] = xr[lane + 64 * j]; s += v[j]; }
  s = wave_sum(s);
  float mean = s * (1.f / DM);
  float q = 0.f;
#pragma unroll
  for (int j = 0; j < 8; j++) { float d = v[j] - mean; q += d * d; }
  q = wave_sum(q);
  float r = rsqrtf(q * (1.f / DM) + 1e-5f);
  __hip_bfloat16* orow = o + row * DM;
#pragma unroll
  for (int j = 0; j < 8; j++) {
    int c = lane + 64 * j;
    orow[c] = __float2bfloat16((v[j] - mean) * r * g[c] + b[c]);
  }
}

// ---------------- layernorm -> fp32 out (final) -----------------------------
__global__ __launch_bounds__(64) void ln_f32_kernel(
    const float* __restrict__ x, const float* __restrict__ g,
    const float* __restrict__ b, float* __restrict__ o) {
  int row = blockIdx.x, lane = threadIdx.x;
  const float* xr = x + row * DM;
  float v[8];
  float s = 0.f;
#pragma unroll
  for (int j = 0; j < 8; j++) { v[j] = xr[lane + 64 * j]; s += v[j]; }
  s = wave_sum(s);
  float mean = s * (1.f / DM);
  float q = 0.f;
#pragma unroll
  for (int j = 0; j < 8; j++) { float d = v[j] - mean; q += d * d; }
  q = wave_sum(q);
  float r = rsqrtf(q * (1.f / DM) + 1e-5f);
  float* orow = o + row * DM;
#pragma unroll
  for (int j = 0; j < 8; j++) {
    int c = lane + 64 * j;
    orow[c] = (v[j] - mean) * r * g[c] + b[c];
  }
}

// ---------------- per-layer weight transpose+cast: W[K][N]f32 -> Wt[N][K]bf16
// segment table (64x64 tiles): wqkv 192 | wo 64 | cwqkv 192 | cwo 64 | w1 256 | w2 256
__global__ __launch_bounds__(256) void transpose_layer_kernel(
    const float* __restrict__ wqkv, const float* __restrict__ wo,
    const float* __restrict__ cwqkv, const float* __restrict__ cwo,
    const float* __restrict__ w1, const float* __restrict__ w2,
    __hip_bfloat16* __restrict__ Wt) {
  int b = blockIdx.x;
  const float* W;
  __hip_bfloat16* O;
  int Kd, Nd;
  if (b < 192)      { W = wqkv;  O = Wt + 0;       Kd = 512;  Nd = 1536; }
  else if (b < 256) { W = wo;    O = Wt + 786432;  Kd = 512;  Nd = 512;  b -= 192; }
  else if (b < 448) { W = cwqkv; O = Wt + 1048576; Kd = 512;  Nd = 1536; b -= 256; }
  else if (b < 512) { W = cwo;   O = Wt + 1835008; Kd = 512;  Nd = 512;  b -= 448; }
  else if (b < 768) { W = w1;    O = Wt + 2097152; Kd = 512;  Nd = 2048; b -= 512; }
  else              { W = w2;    O = Wt + 3145728; Kd = 2048; Nd = 512;  b -= 768; }
  int tn = Nd >> 6;
  int k0 = (b / tn) * 64, n0 = (b % tn) * 64;
  __shared__ float T[64][65];
  int t = threadIdx.x;
  int rr = t >> 4, c4 = (t & 15) * 4;
#pragma unroll
  for (int p = 0; p < 4; p++) {
    int row = rr + p * 16;
    float4 v = *(const float4*)(W + (long)(k0 + row) * Nd + n0 + c4);
    T[row][c4 + 0] = v.x; T[row][c4 + 1] = v.y;
    T[row][c4 + 2] = v.z; T[row][c4 + 3] = v.w;
  }
  __syncthreads();
#pragma unroll
  for (int p = 0; p < 4; p++) {
    int row = rr + p * 16;  // n-index
    ushort4 pk;
    pk.x = f2b(T[c4 + 0][row]); pk.y = f2b(T[c4 + 1][row]);
    pk.z = f2b(T[c4 + 2][row]); pk.w = f2b(T[c4 + 3][row]);
    *(ushort4*)(O + (long)(n0 + row) * Kd + k0 + c4) = pk;
  }
}

// ---------------- bf16 MFMA GEMM: C[M,N] = A[M,K] @ Bt[N,K]^T ---------------
// 128x128 tile, 4 waves (2x2), each wave 64x64 = 4x4 16x16x32 frags, BK=32.
// LDS kc-major: [kc 0..3][row 0..127][8] -> conflict-free ds_read_b128.
__global__ __launch_bounds__(256) void gemm_bf16(
    const __hip_bfloat16* __restrict__ A, int lda,
    const __hip_bfloat16* __restrict__ Bt, int ldb,
    const float* __restrict__ bias,
    const float* __restrict__ residual,
    float* __restrict__ Cf, __hip_bfloat16* __restrict__ Cb,
    int ldc, int K, int relu) {
  __shared__ __attribute__((aligned(16))) __hip_bfloat16 As[4096];
  __shared__ __attribute__((aligned(16))) __hip_bfloat16 Bs[4096];
  const int t = threadIdx.x;
  const int n0 = blockIdx.x * 128, m0 = blockIdx.y * 128;
  const int w = t >> 6, lane = t & 63;
  const int wr = w >> 1, wc = w & 1;
  const int fr = lane & 15, kc = lane >> 4;
  f32x4 acc[4][4] = {};
  for (int k0 = 0; k0 < K; k0 += 32) {
    __syncthreads();
#pragma unroll
    for (int i = 0; i < 2; ++i) {
      int lam = t + 256 * i;
      int row = lam & 127, c = lam >> 7;
      uint4 av = *(const uint4*)(A + (long)(m0 + row) * lda + k0 + c * 8);
      uint4 bv = *(const uint4*)(Bt + (long)(n0 + row) * ldb + k0 + c * 8);
      *(uint4*)(As + c * 1024 + row * 8) = av;
      *(uint4*)(Bs + c * 1024 + row * 8) = bv;
    }
    __syncthreads();
    bf16x8 af[4], bfr[4];
#pragma unroll
    for (int m = 0; m < 4; ++m)
      af[m] = *(const bf16x8*)(As + kc * 1024 + (wr * 64 + m * 16 + fr) * 8);
#pragma unroll
    for (int n = 0; n < 4; ++n)
      bfr[n] = *(const bf16x8*)(Bs + kc * 1024 + (wc * 64 + n * 16 + fr) * 8);
#pragma unroll
    for (int m = 0; m < 4; ++m)
#pragma unroll
      for (int n = 0; n < 4; ++n)
        acc[m][n] = __builtin_amdgcn_mfma_f32_16x16x32_bf16(af[m], bfr[n], acc[m][n], 0, 0, 0);
  }
  const int rbase = m0 + wr * 64, cbase = n0 + wc * 64;
#pragma unroll
  for (int m = 0; m < 4; ++m)
#pragma unroll
    for (int n = 0; n < 4; ++n)
#pragma unroll
      for (int j = 0; j < 4; ++j) {
        int r = rbase + m * 16 + (lane >> 4) * 4 + j;
        int c = cbase + n * 16 + fr;
        float v = acc[m][n][j] + bias[c];
        if (relu) v = fmaxf(v, 0.f);
        if (residual) v += residual[(long)r * ldc + c];
        if (Cf) Cf[(long)r * ldc + c] = v;
        if (Cb) Cb[(long)r * ldc + c] = __float2bfloat16(v);
      }
}

// ---------------- RoPE in-place on bf16 q/k ---------------------------------
__global__ __launch_bounds__(256) void rope_bf16_kernel(
    __hip_bfloat16* __restrict__ q, int ldq,
    __hip_bfloat16* __restrict__ k, int ldk) {
  int row = blockIdx.x;
  int t = threadIdx.x;
  int head = t >> 5, i = t & 31;
  float inv = __expf(-(float)i * (9.210340371976184f / 32.f));
  float ang = (float)row * inv;
  float sn, cs;
  sincosf(ang, &sn, &cs);
  {
    __hip_bfloat16* p = q + (long)row * ldq + head * 64;
    float x1 = __bfloat162float(p[i]), x2 = __bfloat162float(p[i + 32]);
    p[i] = __float2bfloat16(x1 * cs - x2 * sn);
    p[i + 32] = __float2bfloat16(x1 * sn + x2 * cs);
  }
  {
    __hip_bfloat16* p = k + (long)row * ldk + head * 64;
    float x1 = __bfloat162float(p[i]), x2 = __bfloat162float(p[i + 32]);
    p[i] = __float2bfloat16(x1 * cs - x2 * sn);
    p[i + 32] = __float2bfloat16(x1 * sn + x2 * cs);
  }
}

// ---------------- MFMA flash attention --------------------------------------
// grid (SEQ/64, NHEAD), 256 thr = 4 waves; wave w owns q-rows [q0+16w, +16).
// K staged kc-major [c 0..7][krow 0..63][8]; Vt / Ps XOR-swizzled transposed.
__global__ __launch_bounds__(256) void attn_mfma_kernel(
    const __hip_bfloat16* __restrict__ Q, int ldq,
    const __hip_bfloat16* __restrict__ K, int ldk,
    const __hip_bfloat16* __restrict__ V, int ldv,
    const float* __restrict__ mask,
    __hip_bfloat16* __restrict__ O, int ldo, int causal) {
  __shared__ __attribute__((aligned(16))) __hip_bfloat16 Ks[4096];
  __shared__ __attribute__((aligned(16))) __hip_bfloat16 Vt[4096];
  __shared__ __attribute__((aligned(16))) __hip_bfloat16 Ps[4096];
  const int qt = blockIdx.x, head = blockIdx.y;
  const int t = threadIdx.x, w = t >> 6, lane = t & 63;
  const int fr = lane & 15, fk = lane >> 4;
  const int q0 = qt * 64;

  bf16x8 qa[2];
  {
    const __hip_bfloat16* qp = Q + (long)(q0 + w * 16 + fr) * ldq + head * 64;
    qa[0] = *(const bf16x8*)(qp + fk * 8);
    qa[1] = *(const bf16x8*)(qp + 32 + fk * 8);
  }
  float m_i[4], l_i[4];
  f32x4 o_[4] = {};
#pragma unroll
  for (int j = 0; j < 4; j++) { m_i[j] = -1e30f; l_i[j] = 0.f; }

  const int nkt = causal ? (qt + 1) : (SEQ / 64);
  for (int kt = 0; kt < nkt; ++kt) {
    const int kb = kt * 64;
    __syncthreads();
    // stage K (kc-major) and V (transposed, XOR swizzle)
#pragma unroll
    for (int i = 0; i < 2; i++) {
      int lam = t + 256 * i;
      int krow = lam & 63, c = lam >> 6;
      uint4 kv = *(const uint4*)(K + (long)(kb + krow) * ldk + head * 64 + c * 8);
      *(uint4*)(Ks + c * 512 + krow * 8) = kv;
      uint4 vv = *(const uint4*)(V + (long)(kb + krow) * ldv + head * 64 + c * 8);
      const __hip_bfloat16* vs = (const __hip_bfloat16*)&vv;
#pragma unroll
      for (int e = 0; e < 8; e++) {
        int d = c * 8 + e;
        int byte = (d * 128 + krow * 2) ^ ((d & 7) << 4);
        *(__hip_bfloat16*)((char*)Vt + byte) = vs[e];
      }
    }
    __syncthreads();

    // S = Q K^T (rows q, cols k)
    f32x4 sacc[4];
#pragma unroll
    for (int n = 0; n < 4; n++) {
      bf16x8 kb0 = *(const bf16x8*)(Ks + (0 + fk) * 512 + (n * 16 + fr) * 8);
      bf16x8 kb1 = *(const bf16x8*)(Ks + (4 + fk) * 512 + (n * 16 + fr) * 8);
      f32x4 z = {};
      z = __builtin_amdgcn_mfma_f32_16x16x32_bf16(qa[0], kb0, z, 0, 0, 0);
      sacc[n] = __builtin_amdgcn_mfma_f32_16x16x32_bf16(qa[1], kb1, z, 0, 0, 0);
    }

    // online softmax (fp32); output row = (lane>>4)*4+j, col = n*16+fr
    float pr[4][4];
#pragma unroll
    for (int j = 0; j < 4; j++) {
      int qr = q0 + w * 16 + (lane >> 4) * 4 + j;
      float s0[4];
      float rm = -1e30f;
#pragma unroll
      for (int n = 0; n < 4; n++) {
        int ka = kb + n * 16 + fr;
        float sv = sacc[n][j] * 0.125f;
        bool ok = (mask[ka] > 0.f) && (!causal || ka <= qr);
        s0[n] = ok ? sv : -1e30f;
        rm = fmaxf(rm, s0[n]);
      }
#pragma unroll
      for (int off = 1; off < 16; off <<= 1) rm = fmaxf(rm, __shfl_xor(rm, off));
      float nm = fmaxf(m_i[j], rm);
      float f = __expf(m_i[j] - nm);
      m_i[j] = nm;
      float ps = 0.f;
#pragma unroll
      for (int n = 0; n < 4; n++) {
        float p = (s0[n] > -1e29f) ? __expf(s0[n] - nm) : 0.f;
        pr[n][j] = p;
        ps += p;
      }
#pragma unroll
      for (int off = 1; off < 16; off <<= 1) ps += __shfl_xor(ps, off);
      l_i[j] = l_i[j] * f + ps;
#pragma unroll
      for (int n = 0; n < 4; n++) o_[n][j] *= f;
    }

    // write P (bf16, transposed-row layout [q][k] with XOR swizzle)
#pragma unroll
    for (int n = 0; n < 4; n++)
#pragma unroll
      for (int j = 0; j < 4; j++) {
        int prow = w * 16 + (lane >> 4) * 4 + j;
        int col = n * 16 + fr;
        int byte = (prow * 128 + col * 2) ^ ((prow & 7) << 4);
        *(__hip_bfloat16*)((char*)Ps + byte) = __float2bfloat16(pr[n][j]);
      }
    __syncthreads();

    // O += P V
#pragma unroll
    for (int s = 0; s < 2; s++) {
      int prow = w * 16 + fr;
      int pbyte = (prow * 128 + (s * 32 + fk * 8) * 2) ^ ((prow & 7) << 4);
      bf16x8 pa = *(const bf16x8*)((char*)Ps + pbyte);
#pragma unroll
      for (int n = 0; n < 4; n++) {
        int d = n * 16 + fr;
        int vbyte = (d * 128 + (s * 32 + fk * 8) * 2) ^ ((d & 7) << 4);
        bf16x8 vb = *(const bf16x8*)((char*)Vt + vbyte);
        o_[n] = __builtin_amdgcn_mfma_f32_16x16x32_bf16(pa, vb, o_[n], 0, 0, 0);
      }
    }
  }

#pragma unroll
  for (int j = 0; j < 4; j++) {
    float inv = 1.f / fmaxf(l_i[j], 1e-20f);
    int qr = q0 + w * 16 + (lane >> 4) * 4 + j;
#pragma unroll
    for (int n = 0; n < 4; n++)
      O[(long)qr * ldo + head * 64 + n * 16 + fr] = __float2bfloat16(o_[n][j] * inv);
  }
}

// ---------------- generator --------------------------------------------------
__global__ __launch_bounds__(64) void gen_kernel(
    const float* __restrict__ h, const float* __restrict__ gw,
    const float* __restrict__ gb, float* __restrict__ out) {
  int row = blockIdx.x, lane = threadIdx.x;
  float a0 = 0.f, a1 = 0.f, a2 = 0.f;
  for (int k = lane; k < DM; k += 64) {
    float x = h[(long)row * DM + k];
    a0 = fmaf(x, gw[k * 3 + 0], a0);
    a1 = fmaf(x, gw[k * 3 + 1], a1);
    a2 = fmaf(x, gw[k * 3 + 2], a2);
  }
  a0 = wave_sum(a0);
  a1 = wave_sum(a1);
  a2 = wave_sum(a2);
  if (lane == 0) {
    out[row * 3 + 0] = a0 + gb[0];
    out[row * 3 + 1] = a1 + gb[1];
    out[row * 3 + 2] = a2 + gb[2];
  }
}

extern "C" void kernel_launch(void* const* d_in, const int* in_sizes, int n_in,
                              void* d_out, int out_size, void* d_ws, size_t ws_size,
                              hipStream_t stream) {
  const float* trg      = (const float*)d_in[0];
  const float* src_rep  = (const float*)d_in[1];
  const float* src_mask = (const float*)d_in[2];
  const float* emb_w    = (const float*)d_in[3];
  const float* emb_b    = (const float*)d_in[4];
  const float* sa_wqkv  = (const float*)d_in[5];
  const float* sa_bqkv  = (const float*)d_in[6];
  const float* sa_wo    = (const float*)d_in[7];
  const float* sa_bo    = (const float*)d_in[8];
  const float* ca_wqkv  = (const float*)d_in[9];
  const float* ca_bqkv  = (const float*)d_in[10];
  const float* ca_wo    = (const float*)d_in[11];
  const float* ca_bo    = (const float*)d_in[12];
  const float* ffn_w1   = (const float*)d_in[13];
  const float* ffn_b1   = (const float*)d_in[14];
  const float* ffn_w2   = (const float*)d_in[15];
  const float* ffn_b2   = (const float*)d_in[16];
  const float* ln_g     = (const float*)d_in[17];
  const float* ln_b     = (const float*)d_in[18];
  const float* lnf_g    = (const float*)d_in[19];
  const float* lnf_b    = (const float*)d_in[20];
  const float* gen_w    = (const float*)d_in[21];
  const float* gen_b    = (const float*)d_in[22];

  const float* srb = src_rep + (long)PMTN * DM;

  char* wsb = (char*)d_ws;
  float*          X    = (float*)wsb;                              // 4 MB
  __hip_bfloat16* Hb   = (__hip_bfloat16*)(wsb + (4 << 20));       // 2 MB
  __hip_bfloat16* QKV  = (__hip_bfloat16*)(wsb + (6 << 20));       // 6 MB
  __hip_bfloat16* AO   = (__hip_bfloat16*)(wsb + (12 << 20));      // 2 MB
  __hip_bfloat16* SRBb = (__hip_bfloat16*)(wsb + (14 << 20));      // 2 MB
  __hip_bfloat16* Wt   = (__hip_bfloat16*)(wsb + (16 << 20));      // 8 MB
  __hip_bfloat16* MID  = QKV;           // 8 MB, spans QKV+AO (free during FFN)
  float*          Hf   = (float*)QKV;   // final hidden (fp32), reuses QKV

  embed_kernel<<<(SEQ * DM) / 256, 256, 0, stream>>>(trg, emb_w, emb_b, X);
  cast_bf16_kernel<<<(SEQ * DM) / 256, 256, 0, stream>>>(srb, SRBb);

  __hip_bfloat16* wqkvT  = Wt + 0;
  __hip_bfloat16* woT    = Wt + 786432;
  __hip_bfloat16* cwqkvT = Wt + 1048576;
  __hip_bfloat16* cwoT   = Wt + 1835008;
  __hip_bfloat16* w1T    = Wt + 2097152;
  __hip_bfloat16* w2T    = Wt + 3145728;

  for (int li = 0; li < 4; li++) {
    transpose_layer_kernel<<<1024, 256, 0, stream>>>(
        sa_wqkv + (long)li * DM * 3 * DM, sa_wo + (long)li * DM * DM,
        ca_wqkv + (long)li * DM * 3 * DM, ca_wo + (long)li * DM * DM,
        ffn_w1 + (long)li * DM * DFFN, ffn_w2 + (long)li * DFFN * DM, Wt);

    const float* bqkv  = sa_bqkv + (long)li * 3 * DM;
    const float* bo    = sa_bo + (long)li * DM;
    const float* cbqkv = ca_bqkv + (long)li * 3 * DM;
    const float* cbo   = ca_bo + (long)li * DM;
    const float* b1    = ffn_b1 + (long)li * DFFN;
    const float* b2    = ffn_b2 + (long)li * DM;
    const float* g0  = ln_g + (long)(li * 3 + 0) * DM;
    const float* bb0 = ln_b + (long)(li * 3 + 0) * DM;
    const float* g1  = ln_g + (long)(li * 3 + 1) * DM;
    const float* bb1 = ln_b + (long)(li * 3 + 1) * DM;
    const float* g2  = ln_g + (long)(li * 3 + 2) * DM;
    const float* bb2 = ln_b + (long)(li * 3 + 2) * DM;

    // ---- self attention ----
    ln_bf16_kernel<<<SEQ, 64, 0, stream>>>(X, g0, bb0, Hb);
    gemm_bf16<<<dim3(12, 16), 256, 0, stream>>>(
        Hb, DM, wqkvT, DM, bqkv, nullptr, nullptr, QKV, 3 * DM, DM, 0);
    rope_bf16_kernel<<<SEQ, 256, 0, stream>>>(QKV, 3 * DM, QKV + DM, 3 * DM);
    attn_mfma_kernel<<<dim3(SEQ / 64, NHEAD), 256, 0, stream>>>(
        QKV, 3 * DM, QKV + DM, 3 * DM, QKV + 2 * DM, 3 * DM, src_mask, AO, DM, 1);
    gemm_bf16<<<dim3(4, 16), 256, 0, stream>>>(
        AO, DM, woT, DM, bo, X, X, nullptr, DM, DM, 0);

    // ---- cross attention ----
    ln_bf16_kernel<<<SEQ, 64, 0, stream>>>(X, g1, bb1, Hb);
    __hip_bfloat16* Qc = QKV;                       // [2048][512]
    __hip_bfloat16* KVc = QKV + (long)SEQ * DM;     // [2048][1024]
    gemm_bf16<<<dim3(4, 16), 256, 0, stream>>>(
        Hb, DM, cwqkvT, DM, cbqkv, nullptr, nullptr, Qc, DM, DM, 0);
    gemm_bf16<<<dim3(8, 16), 256, 0, stream>>>(
        SRBb, DM, cwqkvT + (long)DM * DM, DM, cbqkv + DM, nullptr, nullptr,
        KVc, 2 * DM, DM, 0);
    rope_bf16_kernel<<<SEQ, 256, 0, stream>>>(Qc, DM, KVc, 2 * DM);
    attn_mfma_kernel<<<dim3(SEQ / 64, NHEAD), 256, 0, stream>>>(
        Qc, DM, KVc, 2 * DM, KVc + DM, 2 * DM, src_mask, AO, DM, 0);
    gemm_bf16<<<dim3(4, 16), 256, 0, stream>>>(
        AO, DM, cwoT, DM, cbo, X, X, nullptr, DM, DM, 0);

    // ---- FFN ----
    ln_bf16_kernel<<<SEQ, 64, 0, stream>>>(X, g2, bb2, Hb);
    gemm_bf16<<<dim3(16, 16), 256, 0, stream>>>(
        Hb, DM, w1T, DM, b1, nullptr, nullptr, MID, DFFN, DM, 1);
    gemm_bf16<<<dim3(4, 16), 256, 0, stream>>>(
        MID, DFFN, w2T, DFFN, b2, X, X, nullptr, DM, DFFN, 0);
  }

  ln_f32_kernel<<<SEQ, 64, 0, stream>>>(X, lnf_g, lnf_b, Hf);
  gen_kernel<<<SEQ, 64, 0, stream>>>(Hf, gen_w, gen_b, (float*)d_out);
}

// Round 4
// 1026.515 us; speedup vs baseline: 18.5160x; 1.6642x over previous
//
#include <hip/hip_runtime.h>
#include <hip/hip_bf16.h>

#define SEQ 2048
#define DM 512
#define NHEAD 8
#define HDIM 64
#define DFFN 2048
#define PMTN 20

typedef __bf16 bf16x8 __attribute__((ext_vector_type(8)));
typedef float f32x4 __attribute__((ext_vector_type(4)));

__device__ __forceinline__ float wave_sum(float v) {
#pragma unroll
  for (int off = 32; off; off >>= 1) v += __shfl_xor(v, off);
  return v;
}

__device__ __forceinline__ unsigned short f2b(float x) {
  __hip_bfloat16 h = __float2bfloat16(x);
  return *(unsigned short*)&h;
}

// ---------------- embed ------------------------------------------------------
__global__ __launch_bounds__(256) void embed_kernel(
    const float* __restrict__ trg, const float* __restrict__ w,
    const float* __restrict__ b, float* __restrict__ X) {
  int idx = blockIdx.x * 256 + threadIdx.x;
  int r = idx >> 9, c = idx & 511;
  float t0 = trg[r * 3 + 0], t1 = trg[r * 3 + 1], t2 = trg[r * 3 + 2];
  X[idx] = t0 * w[c] + t1 * w[512 + c] + t2 * w[1024 + c] + b[c];
}

__global__ __launch_bounds__(256) void cast_bf16_kernel(
    const float* __restrict__ in, __hip_bfloat16* __restrict__ out) {
  int i = blockIdx.x * 256 + threadIdx.x;
  out[i] = __float2bfloat16(in[i]);
}

// ---------------- layernorms -------------------------------------------------
__global__ __launch_bounds__(64) void ln_bf16_kernel(
    const float* __restrict__ x, const float* __restrict__ g,
    const float* __restrict__ b, __hip_bfloat16* __restrict__ o) {
  int row = blockIdx.x, lane = threadIdx.x;
  const float* xr = x + row * DM;
  float v[8];
  float s = 0.f;
#pragma unroll
  for (int j = 0; j < 8; j++) { v[j] = xr[lane + 64 * j]; s += v[j]; }
  s = wave_sum(s);
  float mean = s * (1.f / DM);
  float q = 0.f;
#pragma unroll
  for (int j = 0; j < 8; j++) { float d = v[j] - mean; q += d * d; }
  q = wave_sum(q);
  float r = rsqrtf(q * (1.f / DM) + 1e-5f);
  __hip_bfloat16* orow = o + row * DM;
#pragma unroll
  for (int j = 0; j < 8; j++) {
    int c = lane + 64 * j;
    orow[c] = __float2bfloat16((v[j] - mean) * r * g[c] + b[c]);
  }
}

__global__ __launch_bounds__(64) void ln_f32_kernel(
    const float* __restrict__ x, const float* __restrict__ g,
    const float* __restrict__ b, float* __restrict__ o) {
  int row = blockIdx.x, lane = threadIdx.x;
  const float* xr = x + row * DM;
  float v[8];
  float s = 0.f;
#pragma unroll
  for (int j = 0; j < 8; j++) { v[j] = xr[lane + 64 * j]; s += v[j]; }
  s = wave_sum(s);
  float mean = s * (1.f / DM);
  float q = 0.f;
#pragma unroll
  for (int j = 0; j < 8; j++) { float d = v[j] - mean; q += d * d; }
  q = wave_sum(q);
  float r = rsqrtf(q * (1.f / DM) + 1e-5f);
  float* orow = o + row * DM;
#pragma unroll
  for (int j = 0; j < 8; j++) {
    int c = lane + 64 * j;
    orow[c] = (v[j] - mean) * r * g[c] + b[c];
  }
}

// ---------------- per-layer weight transpose+cast ---------------------------
__global__ __launch_bounds__(256) void transpose_layer_kernel(
    const float* __restrict__ wqkv, const float* __restrict__ wo,
    const float* __restrict__ cwqkv, const float* __restrict__ cwo,
    const float* __restrict__ w1, const float* __restrict__ w2,
    __hip_bfloat16* __restrict__ Wt) {
  int b = blockIdx.x;
  const float* W;
  __hip_bfloat16* O;
  int Kd, Nd;
  if (b < 192)      { W = wqkv;  O = Wt + 0;       Kd = 512;  Nd = 1536; }
  else if (b < 256) { W = wo;    O = Wt + 786432;  Kd = 512;  Nd = 512;  b -= 192; }
  else if (b < 448) { W = cwqkv; O = Wt + 1048576; Kd = 512;  Nd = 1536; b -= 256; }
  else if (b < 512) { W = cwo;   O = Wt + 1835008; Kd = 512;  Nd = 512;  b -= 448; }
  else if (b < 768) { W = w1;    O = Wt + 2097152; Kd = 512;  Nd = 2048; b -= 512; }
  else              { W = w2;    O = Wt + 3145728; Kd = 2048; Nd = 512;  b -= 768; }
  int tn = Nd >> 6;
  int k0 = (b / tn) * 64, n0 = (b % tn) * 64;
  __shared__ float T[64][65];
  int t = threadIdx.x;
  int rr = t >> 4, c4 = (t & 15) * 4;
#pragma unroll
  for (int p = 0; p < 4; p++) {
    int row = rr + p * 16;
    float4 v = *(const float4*)(W + (long)(k0 + row) * Nd + n0 + c4);
    T[row][c4 + 0] = v.x; T[row][c4 + 1] = v.y;
    T[row][c4 + 2] = v.z; T[row][c4 + 3] = v.w;
  }
  __syncthreads();
#pragma unroll
  for (int p = 0; p < 4; p++) {
    int row = rr + p * 16;
    ushort4 pk;
    pk.x = f2b(T[c4 + 0][row]); pk.y = f2b(T[c4 + 1][row]);
    pk.z = f2b(T[c4 + 2][row]); pk.w = f2b(T[c4 + 3][row]);
    *(ushort4*)(O + (long)(n0 + row) * Kd + k0 + c4) = pk;
  }
}

// ---------------- bf16 MFMA GEMM, 64x64 tile, BK=64, double-buffered --------
// 4 waves (2x2), each 32x32 (2x2 16x16x32 frags). LDS kc-major [kc8][row64][8].
__global__ __launch_bounds__(256) void gemm_bf16_64(
    const __hip_bfloat16* __restrict__ A, int lda,
    const __hip_bfloat16* __restrict__ Bt, int ldb,
    const float* __restrict__ bias,
    const float* __restrict__ residual,
    float* __restrict__ Cf, __hip_bfloat16* __restrict__ Cb,
    int ldc, int K, int relu) {
  __shared__ __attribute__((aligned(16))) __hip_bfloat16 As[2][4096];
  __shared__ __attribute__((aligned(16))) __hip_bfloat16 Bs[2][4096];
  const int t = threadIdx.x;
  const int n0 = blockIdx.x * 64, m0 = blockIdx.y * 64;
  const int w = t >> 6, lane = t & 63;
  const int wr = w >> 1, wc = w & 1;
  const int fr = lane & 15, fk = lane >> 4;
  const int r0 = t & 63, c0 = t >> 6;  // staging: row, k-chunk
  const __hip_bfloat16* Arow = A + (long)(m0 + r0) * lda;
  const __hip_bfloat16* Brow = Bt + (long)(n0 + r0) * ldb;

  uint4 ra0 = *(const uint4*)(Arow + c0 * 8);
  uint4 ra1 = *(const uint4*)(Arow + (c0 + 4) * 8);
  uint4 rb0 = *(const uint4*)(Brow + c0 * 8);
  uint4 rb1 = *(const uint4*)(Brow + (c0 + 4) * 8);
  *(uint4*)(&As[0][(c0 * 64 + r0) * 8]) = ra0;
  *(uint4*)(&As[0][((c0 + 4) * 64 + r0) * 8]) = ra1;
  *(uint4*)(&Bs[0][(c0 * 64 + r0) * 8]) = rb0;
  *(uint4*)(&Bs[0][((c0 + 4) * 64 + r0) * 8]) = rb1;
  __syncthreads();

  f32x4 acc[2][2] = {};
  const int NK = K >> 6;
  for (int ks = 0; ks < NK; ++ks) {
    const int cur = ks & 1;
    if (ks + 1 < NK) {
      const int ko = (ks + 1) << 6;
      ra0 = *(const uint4*)(Arow + ko + c0 * 8);
      ra1 = *(const uint4*)(Arow + ko + (c0 + 4) * 8);
      rb0 = *(const uint4*)(Brow + ko + c0 * 8);
      rb1 = *(const uint4*)(Brow + ko + (c0 + 4) * 8);
    }
#pragma unroll
    for (int kk = 0; kk < 2; ++kk) {
      const int kc = kk * 4 + fk;
      bf16x8 a0 = *(const bf16x8*)(&As[cur][(kc * 64 + wr * 32 + fr) * 8]);
      bf16x8 a1 = *(const bf16x8*)(&As[cur][(kc * 64 + wr * 32 + 16 + fr) * 8]);
      bf16x8 b0 = *(const bf16x8*)(&Bs[cur][(kc * 64 + wc * 32 + fr) * 8]);
      bf16x8 b1 = *(const bf16x8*)(&Bs[cur][(kc * 64 + wc * 32 + 16 + fr) * 8]);
      acc[0][0] = __builtin_amdgcn_mfma_f32_16x16x32_bf16(a0, b0, acc[0][0], 0, 0, 0);
      acc[0][1] = __builtin_amdgcn_mfma_f32_16x16x32_bf16(a0, b1, acc[0][1], 0, 0, 0);
      acc[1][0] = __builtin_amdgcn_mfma_f32_16x16x32_bf16(a1, b0, acc[1][0], 0, 0, 0);
      acc[1][1] = __builtin_amdgcn_mfma_f32_16x16x32_bf16(a1, b1, acc[1][1], 0, 0, 0);
    }
    if (ks + 1 < NK) {
      const int nxt = cur ^ 1;
      *(uint4*)(&As[nxt][(c0 * 64 + r0) * 8]) = ra0;
      *(uint4*)(&As[nxt][((c0 + 4) * 64 + r0) * 8]) = ra1;
      *(uint4*)(&Bs[nxt][(c0 * 64 + r0) * 8]) = rb0;
      *(uint4*)(&Bs[nxt][((c0 + 4) * 64 + r0) * 8]) = rb1;
    }
    __syncthreads();
  }

#pragma unroll
  for (int m = 0; m < 2; ++m)
#pragma unroll
    for (int n = 0; n < 2; ++n)
#pragma unroll
      for (int j = 0; j < 4; ++j) {
        int r = m0 + wr * 32 + m * 16 + fk * 4 + j;
        int c = n0 + wc * 32 + n * 16 + fr;
        float v = acc[m][n][j] + bias[c];
        if (relu) v = fmaxf(v, 0.f);
        if (residual) v += residual[(long)r * ldc + c];
        if (Cf) Cf[(long)r * ldc + c] = v;
        if (Cb) Cb[(long)r * ldc + c] = __float2bfloat16(v);
      }
}

// ---------------- RoPE in-place on bf16 q/k ---------------------------------
__global__ __launch_bounds__(256) void rope_bf16_kernel(
    __hip_bfloat16* __restrict__ q, int ldq,
    __hip_bfloat16* __restrict__ k, int ldk) {
  int row = blockIdx.x;
  int t = threadIdx.x;
  int head = t >> 5, i = t & 31;
  float inv = __expf(-(float)i * (9.210340371976184f / 32.f));
  float ang = (float)row * inv;
  float sn, cs;
  sincosf(ang, &sn, &cs);
  {
    __hip_bfloat16* p = q + (long)row * ldq + head * 64;
    float x1 = __bfloat162float(p[i]), x2 = __bfloat162float(p[i + 32]);
    p[i] = __float2bfloat16(x1 * cs - x2 * sn);
    p[i + 32] = __float2bfloat16(x1 * sn + x2 * cs);
  }
  {
    __hip_bfloat16* p = k + (long)row * ldk + head * 64;
    float x1 = __bfloat162float(p[i]), x2 = __bfloat162float(p[i + 32]);
    p[i] = __float2bfloat16(x1 * cs - x2 * sn);
    p[i + 32] = __float2bfloat16(x1 * sn + x2 * cs);
  }
}

// ---------------- split-KV MFMA flash attention partial ---------------------
// grid (32 qt, 4 chunk, 8 head); chunk = 512 kv (8 tiles of 64).
// Writes unnormalized partial O (f32) and per-row (m,l).
__global__ __launch_bounds__(256) void attn_part_kernel(
    const __hip_bfloat16* __restrict__ Q, int ldq,
    const __hip_bfloat16* __restrict__ K, int ldk,
    const __hip_bfloat16* __restrict__ V, int ldv,
    const float* __restrict__ mask,
    float* __restrict__ Op, float* __restrict__ Ml, int causal) {
  const int qt = blockIdx.x, ch = blockIdx.y, head = blockIdx.z;
  if (causal && ch > (qt >> 3)) return;
  const int ktiles = causal ? min(8, (((qt + 1) << 6) - (ch << 9) + 63) >> 6) : 8;

  __shared__ __attribute__((aligned(16))) __hip_bfloat16 Ks[4096];
  __shared__ __attribute__((aligned(16))) __hip_bfloat16 Vt[4096];
  __shared__ __attribute__((aligned(16))) __hip_bfloat16 Ps[4096];
  const int t = threadIdx.x, w = t >> 6, lane = t & 63;
  const int fr = lane & 15, fk = lane >> 4;
  const int q0 = qt * 64;

  bf16x8 qa[2];
  {
    const __hip_bfloat16* qp = Q + (long)(q0 + w * 16 + fr) * ldq + head * 64;
    qa[0] = *(const bf16x8*)(qp + fk * 8);
    qa[1] = *(const bf16x8*)(qp + 32 + fk * 8);
  }
  float m_i[4], l_i[4];
  f32x4 o_[4] = {};
#pragma unroll
  for (int j = 0; j < 4; j++) { m_i[j] = -1e30f; l_i[j] = 0.f; }

  for (int kt = 0; kt < ktiles; ++kt) {
    const int kb = (ch << 9) + kt * 64;
    __syncthreads();
#pragma unroll
    for (int i = 0; i < 2; i++) {
      int lam = t + 256 * i;
      int krow = lam & 63, c = lam >> 6;
      uint4 kv = *(const uint4*)(K + (long)(kb + krow) * ldk + head * 64 + c * 8);
      *(uint4*)(Ks + c * 512 + krow * 8) = kv;
      uint4 vv = *(const uint4*)(V + (long)(kb + krow) * ldv + head * 64 + c * 8);
      const __hip_bfloat16* vs = (const __hip_bfloat16*)&vv;
#pragma unroll
      for (int e = 0; e < 8; e++) {
        int d = c * 8 + e;
        int byte = (d * 128 + krow * 2) ^ ((d & 7) << 4);
        *(__hip_bfloat16*)((char*)Vt + byte) = vs[e];
      }
    }
    __syncthreads();

    f32x4 sacc[4];
#pragma unroll
    for (int n = 0; n < 4; n++) {
      bf16x8 kb0 = *(const bf16x8*)(Ks + (0 + fk) * 512 + (n * 16 + fr) * 8);
      bf16x8 kb1 = *(const bf16x8*)(Ks + (4 + fk) * 512 + (n * 16 + fr) * 8);
      f32x4 z = {};
      z = __builtin_amdgcn_mfma_f32_16x16x32_bf16(qa[0], kb0, z, 0, 0, 0);
      sacc[n] = __builtin_amdgcn_mfma_f32_16x16x32_bf16(qa[1], kb1, z, 0, 0, 0);
    }

    float pr[4][4];
#pragma unroll
    for (int j = 0; j < 4; j++) {
      int qr = q0 + w * 16 + (lane >> 4) * 4 + j;
      float s0[4];
      float rm = -1e30f;
#pragma unroll
      for (int n = 0; n < 4; n++) {
        int ka = kb + n * 16 + fr;
        float sv = sacc[n][j] * 0.125f;
        bool ok = (mask[ka] > 0.f) && (!causal || ka <= qr);
        s0[n] = ok ? sv : -1e30f;
        rm = fmaxf(rm, s0[n]);
      }
#pragma unroll
      for (int off = 1; off < 16; off <<= 1) rm = fmaxf(rm, __shfl_xor(rm, off));
      float nm = fmaxf(m_i[j], rm);
      float f = __expf(m_i[j] - nm);
      m_i[j] = nm;
      float ps = 0.f;
#pragma unroll
      for (int n = 0; n < 4; n++) {
        float p = (s0[n] > -1e29f) ? __expf(s0[n] - nm) : 0.f;
        pr[n][j] = p;
        ps += p;
      }
#pragma unroll
      for (int off = 1; off < 16; off <<= 1) ps += __shfl_xor(ps, off);
      l_i[j] = l_i[j] * f + ps;
#pragma unroll
      for (int n = 0; n < 4; n++) o_[n][j] *= f;
    }

#pragma unroll
    for (int n = 0; n < 4; n++)
#pragma unroll
      for (int j = 0; j < 4; j++) {
        int prow = w * 16 + (lane >> 4) * 4 + j;
        int col = n * 16 + fr;
        int byte = (prow * 128 + col * 2) ^ ((prow & 7) << 4);
        *(__hip_bfloat16*)((char*)Ps + byte) = __float2bfloat16(pr[n][j]);
      }
    __syncthreads();

#pragma unroll
    for (int s = 0; s < 2; s++) {
      int prow = w * 16 + fr;
      int pbyte = (prow * 128 + (s * 32 + fk * 8) * 2) ^ ((prow & 7) << 4);
      bf16x8 pa = *(const bf16x8*)((char*)Ps + pbyte);
#pragma unroll
      for (int n = 0; n < 4; n++) {
        int d = n * 16 + fr;
        int vbyte = (d * 128 + (s * 32 + fk * 8) * 2) ^ ((d & 7) << 4);
        bf16x8 vb = *(const bf16x8*)((char*)Vt + vbyte);
        o_[n] = __builtin_amdgcn_mfma_f32_16x16x32_bf16(pa, vb, o_[n], 0, 0, 0);
      }
    }
  }

  const long bid = (long)(head * 32 + qt) * 4 + ch;
  float* Ob = Op + bid * 4096;
#pragma unroll
  for (int j = 0; j < 4; j++) {
    int row = w * 16 + (lane >> 4) * 4 + j;
#pragma unroll
    for (int n = 0; n < 4; n++) Ob[row * 64 + n * 16 + fr] = o_[n][j];
    if (fr == 0) {
      Ml[bid * 128 + row * 2 + 0] = m_i[j];
      Ml[bid * 128 + row * 2 + 1] = l_i[j];
    }
  }
}

// ---------------- combine partials -> bf16 O --------------------------------
__global__ __launch_bounds__(256) void attn_combine_kernel(
    const float* __restrict__ Op, const float* __restrict__ Ml,
    __hip_bfloat16* __restrict__ O, int ldo, int causal) {
  const int qt = blockIdx.x, head = blockIdx.y;
  const int nc = causal ? (qt >> 3) + 1 : 4;
  const int t = threadIdx.x;
  const int row = t >> 2, c4 = (t & 3) * 16;
  const long bid0 = (long)(head * 32 + qt) * 4;

  float mv[4], lv[4];
  float M = -1e30f;
  for (int c = 0; c < nc; c++) {
    mv[c] = Ml[(bid0 + c) * 128 + row * 2 + 0];
    lv[c] = Ml[(bid0 + c) * 128 + row * 2 + 1];
    M = fmaxf(M, mv[c]);
  }
  float L = 0.f;
  float wgt[4];
  for (int c = 0; c < nc; c++) {
    wgt[c] = __expf(mv[c] - M);
    L += wgt[c] * lv[c];
  }
  float invL = 1.f / fmaxf(L, 1e-20f);
  f32x4 acc[4] = {};
  for (int c = 0; c < nc; c++) {
    const float* base = Op + (bid0 + c) * 4096 + row * 64 + c4;
#pragma unroll
    for (int i = 0; i < 4; i++) {
      f32x4 v = *(const f32x4*)(base + i * 4);
      acc[i] += wgt[c] * v;
    }
  }
  __hip_bfloat16* orow = O + (long)(qt * 64 + row) * ldo + head * 64 + c4;
#pragma unroll
  for (int i = 0; i < 4; i++)
#pragma unroll
    for (int e = 0; e < 4; e++) orow[i * 4 + e] = __float2bfloat16(acc[i][e] * invL);
}

// ---------------- direct attn (fallback if ws too small) --------------------
__global__ __launch_bounds__(256) void attn_mfma_kernel(
    const __hip_bfloat16* __restrict__ Q, int ldq,
    const __hip_bfloat16* __restrict__ K, int ldk,
    const __hip_bfloat16* __restrict__ V, int ldv,
    const float* __restrict__ mask,
    __hip_bfloat16* __restrict__ O, int ldo, int causal) {
  __shared__ __attribute__((aligned(16))) __hip_bfloat16 Ks[4096];
  __shared__ __attribute__((aligned(16))) __hip_bfloat16 Vt[4096];
  __shared__ __attribute__((aligned(16))) __hip_bfloat16 Ps[4096];
  const int qt = blockIdx.x, head = blockIdx.y;
  const int t = threadIdx.x, w = t >> 6, lane = t & 63;
  const int fr = lane & 15, fk = lane >> 4;
  const int q0 = qt * 64;
  bf16x8 qa[2];
  {
    const __hip_bfloat16* qp = Q + (long)(q0 + w * 16 + fr) * ldq + head * 64;
    qa[0] = *(const bf16x8*)(qp + fk * 8);
    qa[1] = *(const bf16x8*)(qp + 32 + fk * 8);
  }
  float m_i[4], l_i[4];
  f32x4 o_[4] = {};
#pragma unroll
  for (int j = 0; j < 4; j++) { m_i[j] = -1e30f; l_i[j] = 0.f; }
  const int nkt = causal ? (qt + 1) : (SEQ / 64);
  for (int kt = 0; kt < nkt; ++kt) {
    const int kb = kt * 64;
    __syncthreads();
#pragma unroll
    for (int i = 0; i < 2; i++) {
      int lam = t + 256 * i;
      int krow = lam & 63, c = lam >> 6;
      uint4 kv = *(const uint4*)(K + (long)(kb + krow) * ldk + head * 64 + c * 8);
      *(uint4*)(Ks + c * 512 + krow * 8) = kv;
      uint4 vv = *(const uint4*)(V + (long)(kb + krow) * ldv + head * 64 + c * 8);
      const __hip_bfloat16* vs = (const __hip_bfloat16*)&vv;
#pragma unroll
      for (int e = 0; e < 8; e++) {
        int d = c * 8 + e;
        int byte = (d * 128 + krow * 2) ^ ((d & 7) << 4);
        *(__hip_bfloat16*)((char*)Vt + byte) = vs[e];
      }
    }
    __syncthreads();
    f32x4 sacc[4];
#pragma unroll
    for (int n = 0; n < 4; n++) {
      bf16x8 kb0 = *(const bf16x8*)(Ks + (0 + fk) * 512 + (n * 16 + fr) * 8);
      bf16x8 kb1 = *(const bf16x8*)(Ks + (4 + fk) * 512 + (n * 16 + fr) * 8);
      f32x4 z = {};
      z = __builtin_amdgcn_mfma_f32_16x16x32_bf16(qa[0], kb0, z, 0, 0, 0);
      sacc[n] = __builtin_amdgcn_mfma_f32_16x16x32_bf16(qa[1], kb1, z, 0, 0, 0);
    }
    float pr[4][4];
#pragma unroll
    for (int j = 0; j < 4; j++) {
      int qr = q0 + w * 16 + (lane >> 4) * 4 + j;
      float s0[4];
      float rm = -1e30f;
#pragma unroll
      for (int n = 0; n < 4; n++) {
        int ka = kb + n * 16 + fr;
        float sv = sacc[n][j] * 0.125f;
        bool ok = (mask[ka] > 0.f) && (!causal || ka <= qr);
        s0[n] = ok ? sv : -1e30f;
        rm = fmaxf(rm, s0[n]);
      }
#pragma unroll
      for (int off = 1; off < 16; off <<= 1) rm = fmaxf(rm, __shfl_xor(rm, off));
      float nm = fmaxf(m_i[j], rm);
      float f = __expf(m_i[j] - nm);
      m_i[j] = nm;
      float ps = 0.f;
#pragma unroll
      for (int n = 0; n < 4; n++) {
        float p = (s0[n] > -1e29f) ? __expf(s0[n] - nm) : 0.f;
        pr[n][j] = p;
        ps += p;
      }
#pragma unroll
      for (int off = 1; off < 16; off <<= 1) ps += __shfl_xor(ps, off);
      l_i[j] = l_i[j] * f + ps;
#pragma unroll
      for (int n = 0; n < 4; n++) o_[n][j] *= f;
    }
#pragma unroll
    for (int n = 0; n < 4; n++)
#pragma unroll
      for (int j = 0; j < 4; j++) {
        int prow = w * 16 + (lane >> 4) * 4 + j;
        int col = n * 16 + fr;
        int byte = (prow * 128 + col * 2) ^ ((prow & 7) << 4);
        *(__hip_bfloat16*)((char*)Ps + byte) = __float2bfloat16(pr[n][j]);
      }
    __syncthreads();
#pragma unroll
    for (int s = 0; s < 2; s++) {
      int prow = w * 16 + fr;
      int pbyte = (prow * 128 + (s * 32 + fk * 8) * 2) ^ ((prow & 7) << 4);
      bf16x8 pa = *(const bf16x8*)((char*)Ps + pbyte);
#pragma unroll
      for (int n = 0; n < 4; n++) {
        int d = n * 16 + fr;
        int vbyte = (d * 128 + (s * 32 + fk * 8) * 2) ^ ((d & 7) << 4);
        bf16x8 vb = *(const bf16x8*)((char*)Vt + vbyte);
        o_[n] = __builtin_amdgcn_mfma_f32_16x16x32_bf16(pa, vb, o_[n], 0, 0, 0);
      }
    }
  }
#pragma unroll
  for (int j = 0; j < 4; j++) {
    float inv = 1.f / fmaxf(l_i[j], 1e-20f);
    int qr = q0 + w * 16 + (lane >> 4) * 4 + j;
#pragma unroll
    for (int n = 0; n < 4; n++)
      O[(long)qr * ldo + head * 64 + n * 16 + fr] = __float2bfloat16(o_[n][j] * inv);
  }
}

// ---------------- generator --------------------------------------------------
__global__ __launch_bounds__(64) void gen_kernel(
    const float* __restrict__ h, const float* __restrict__ gw,
    const float* __restrict__ gb, float* __restrict__ out) {
  int row = blockIdx.x, lane = threadIdx.x;
  float a0 = 0.f, a1 = 0.f, a2 = 0.f;
  for (int k = lane; k < DM; k += 64) {
    float x = h[(long)row * DM + k];
    a0 = fmaf(x, gw[k * 3 + 0], a0);
    a1 = fmaf(x, gw[k * 3 + 1], a1);
    a2 = fmaf(x, gw[k * 3 + 2], a2);
  }
  a0 = wave_sum(a0);
  a1 = wave_sum(a1);
  a2 = wave_sum(a2);
  if (lane == 0) {
    out[row * 3 + 0] = a0 + gb[0];
    out[row * 3 + 1] = a1 + gb[1];
    out[row * 3 + 2] = a2 + gb[2];
  }
}

extern "C" void kernel_launch(void* const* d_in, const int* in_sizes, int n_in,
                              void* d_out, int out_size, void* d_ws, size_t ws_size,
                              hipStream_t stream) {
  const float* trg      = (const float*)d_in[0];
  const float* src_rep  = (const float*)d_in[1];
  const float* src_mask = (const float*)d_in[2];
  const float* emb_w    = (const float*)d_in[3];
  const float* emb_b    = (const float*)d_in[4];
  const float* sa_wqkv  = (const float*)d_in[5];
  const float* sa_bqkv  = (const float*)d_in[6];
  const float* sa_wo    = (const float*)d_in[7];
  const float* sa_bo    = (const float*)d_in[8];
  const float* ca_wqkv  = (const float*)d_in[9];
  const float* ca_bqkv  = (const float*)d_in[10];
  const float* ca_wo    = (const float*)d_in[11];
  const float* ca_bo    = (const float*)d_in[12];
  const float* ffn_w1   = (const float*)d_in[13];
  const float* ffn_b1   = (const float*)d_in[14];
  const float* ffn_w2   = (const float*)d_in[15];
  const float* ffn_b2   = (const float*)d_in[16];
  const float* ln_g     = (const float*)d_in[17];
  const float* ln_b     = (const float*)d_in[18];
  const float* lnf_g    = (const float*)d_in[19];
  const float* lnf_b    = (const float*)d_in[20];
  const float* gen_w    = (const float*)d_in[21];
  const float* gen_b    = (const float*)d_in[22];

  const float* srb = src_rep + (long)PMTN * DM;

  char* wsb = (char*)d_ws;
  float*          X    = (float*)wsb;                              // 4 MB
  __hip_bfloat16* Hb   = (__hip_bfloat16*)(wsb + (4 << 20));       // 2 MB
  __hip_bfloat16* QKV  = (__hip_bfloat16*)(wsb + (6 << 20));       // 6 MB
  __hip_bfloat16* AO   = (__hip_bfloat16*)(wsb + (12 << 20));      // 2 MB
  __hip_bfloat16* SRBb = (__hip_bfloat16*)(wsb + (14 << 20));      // 2 MB
  __hip_bfloat16* Wt   = (__hip_bfloat16*)(wsb + (16 << 20));      // 8 MB
  float*          Op   = (float*)(wsb + (24l << 20));              // 16 MB
  float*          Ml   = (float*)(wsb + (40l << 20));              // 0.5 MB
  __hip_bfloat16* MID  = QKV;
  float*          Hf   = (float*)QKV;
  const bool use_split = ws_size >= (41ul << 20);

  embed_kernel<<<(SEQ * DM) / 256, 256, 0, stream>>>(trg, emb_w, emb_b, X);
  cast_bf16_kernel<<<(SEQ * DM) / 256, 256, 0, stream>>>(srb, SRBb);

  __hip_bfloat16* wqkvT  = Wt + 0;
  __hip_bfloat16* woT    = Wt + 786432;
  __hip_bfloat16* cwqkvT = Wt + 1048576;
  __hip_bfloat16* cwoT   = Wt + 1835008;
  __hip_bfloat16* w1T    = Wt + 2097152;
  __hip_bfloat16* w2T    = Wt + 3145728;

  for (int li = 0; li < 4; li++) {
    transpose_layer_kernel<<<1024, 256, 0, stream>>>(
        sa_wqkv + (long)li * DM * 3 * DM, sa_wo + (long)li * DM * DM,
        ca_wqkv + (long)li * DM * 3 * DM, ca_wo + (long)li * DM * DM,
        ffn_w1 + (long)li * DM * DFFN, ffn_w2 + (long)li * DFFN * DM, Wt);

    const float* bqkv  = sa_bqkv + (long)li * 3 * DM;
    const float* bo    = sa_bo + (long)li * DM;
    const float* cbqkv = ca_bqkv + (long)li * 3 * DM;
    const float* cbo   = ca_bo + (long)li * DM;
    const float* b1    = ffn_b1 + (long)li * DFFN;
    const float* b2    = ffn_b2 + (long)li * DM;
    const float* g0  = ln_g + (long)(li * 3 + 0) * DM;
    const float* bb0 = ln_b + (long)(li * 3 + 0) * DM;
    const float* g1  = ln_g + (long)(li * 3 + 1) * DM;
    const float* bb1 = ln_b + (long)(li * 3 + 1) * DM;
    const float* g2  = ln_g + (long)(li * 3 + 2) * DM;
    const float* bb2 = ln_b + (long)(li * 3 + 2) * DM;

    // ---- self attention ----
    ln_bf16_kernel<<<SEQ, 64, 0, stream>>>(X, g0, bb0, Hb);
    gemm_bf16_64<<<dim3(24, 32), 256, 0, stream>>>(
        Hb, DM, wqkvT, DM, bqkv, nullptr, nullptr, QKV, 3 * DM, DM, 0);
    rope_bf16_kernel<<<SEQ, 256, 0, stream>>>(QKV, 3 * DM, QKV + DM, 3 * DM);
    if (use_split) {
      attn_part_kernel<<<dim3(32, 4, 8), 256, 0, stream>>>(
          QKV, 3 * DM, QKV + DM, 3 * DM, QKV + 2 * DM, 3 * DM, src_mask, Op, Ml, 1);
      attn_combine_kernel<<<dim3(32, 8), 256, 0, stream>>>(Op, Ml, AO, DM, 1);
    } else {
      attn_mfma_kernel<<<dim3(32, 8), 256, 0, stream>>>(
          QKV, 3 * DM, QKV + DM, 3 * DM, QKV + 2 * DM, 3 * DM, src_mask, AO, DM, 1);
    }
    gemm_bf16_64<<<dim3(8, 32), 256, 0, stream>>>(
        AO, DM, woT, DM, bo, X, X, nullptr, DM, DM, 0);

    // ---- cross attention ----
    ln_bf16_kernel<<<SEQ, 64, 0, stream>>>(X, g1, bb1, Hb);
    __hip_bfloat16* Qc = QKV;
    __hip_bfloat16* KVc = QKV + (long)SEQ * DM;
    gemm_bf16_64<<<dim3(8, 32), 256, 0, stream>>>(
        Hb, DM, cwqkvT, DM, cbqkv, nullptr, nullptr, Qc, DM, DM, 0);
    gemm_bf16_64<<<dim3(16, 32), 256, 0, stream>>>(
        SRBb, DM, cwqkvT + (long)DM * DM, DM, cbqkv + DM, nullptr, nullptr,
        KVc, 2 * DM, DM, 0);
    rope_bf16_kernel<<<SEQ, 256, 0, stream>>>(Qc, DM, KVc, 2 * DM);
    if (use_split) {
      attn_part_kernel<<<dim3(32, 4, 8), 256, 0, stream>>>(
          Qc, DM, KVc, 2 * DM, KVc + DM, 2 * DM, src_mask, Op, Ml, 0);
      attn_combine_kernel<<<dim3(32, 8), 256, 0, stream>>>(Op, Ml, AO, DM, 0);
    } else {
      attn_mfma_kernel<<<dim3(32, 8), 256, 0, stream>>>(
          Qc, DM, KVc, 2 * DM, KVc + DM, 2 * DM, src_mask, AO, DM, 0);
    }
    gemm_bf16_64<<<dim3(8, 32), 256, 0, stream>>>(
        AO, DM, cwoT, DM, cbo, X, X, nullptr, DM, DM, 0);

    // ---- FFN ----
    ln_bf16_kernel<<<SEQ, 64, 0, stream>>>(X, g2, bb2, Hb);
    gemm_bf16_64<<<dim3(32, 32), 256, 0, stream>>>(
        Hb, DM, w1T, DM, b1, nullptr, nullptr, MID, DFFN, DM, 1);
    gemm_bf16_64<<<dim3(8, 32), 256, 0, stream>>>(
        MID, DFFN, w2T, DFFN, b2, X, X, nullptr, DM, DFFN, 0);
  }

  ln_f32_kernel<<<SEQ, 64, 0, stream>>>(X, lnf_g, lnf_b, Hf);
  gen_kernel<<<SEQ, 64, 0, stream>>>(Hf, gen_w, gen_b, (float*)d_out);
}